// Round 3
// baseline (398.282 us; speedup 1.0000x reference)
//
#include <hip/hip_runtime.h>
#include <stdint.h>

typedef unsigned short u16;
typedef unsigned int u32;
typedef __bf16 bf16x8 __attribute__((ext_vector_type(8)));
typedef float floatx4 __attribute__((ext_vector_type(4)));

static __device__ __forceinline__ float bf2f(u16 u) {
  union { u32 i; float f; } v; v.i = ((u32)u) << 16; return v.f;
}
static __device__ __forceinline__ u16 f2bf(float f) {
  union { float f; u32 i; } v; v.f = f;
  u32 u = v.i;
  return (u16)((u + 0x7fffu + ((u >> 16) & 1u)) >> 16);  // RNE
}

// ---- edge dtype detector: int64 layout <=> odd int32 words are all high-halves (0) ----
__global__ void k_edgemode(const int* __restrict__ ei, int* __restrict__ flag) {
  int t = threadIdx.x;                       // 64 threads, 1 wave
  int v = ei[2 * t + 1];                     // odd positions among first 128 ints
  unsigned long long b = __ballot(v == 0);
  if (t == 0) *flag = (b == ~0ull) ? 1 : 0;  // all zero -> int64 buffer
}

static __device__ __forceinline__ int edge_src(const int* ei, int E, int i, int m64) {
  return m64 ? ei[2 * (size_t)i] : ei[i];
}
static __device__ __forceinline__ int edge_dst(const int* ei, int E, int i, int m64) {
  return m64 ? ei[2 * (size_t)E + 2 * (size_t)i] : ei[(size_t)E + i];
}

// ---- W transpose + fp32->bf16: Wt[n][k] = bf16(W[k][n]) ----
__global__ void k_transpose(const float* __restrict__ W1, const float* __restrict__ W2,
                            u16* __restrict__ Wt1, u16* __restrict__ Wt2) {
  int i = blockIdx.x * 256 + threadIdx.x;
  if (i < 256 * 128) {
    int k = i >> 7, c = i & 127;
    Wt1[c * 256 + k] = f2bf(W1[i]);
  } else {
    int j = i - 256 * 128;
    if (j < 128 * 64) {
      int k = j >> 6, c = j & 63;
      Wt2[c * 128 + k] = f2bf(W2[j]);
    }
  }
}

// ======== bucket partition: bucket b = dst>>7 (128 nodes per bucket) ========
#define CHUNK 2048

// per-chunk LDS histogram -> global bucket counts
__global__ void k_count(const int* __restrict__ ei, int E, const int* __restrict__ flag,
                        int* __restrict__ bucket_cnt, int NB) {
  __shared__ int h[1024];
  const int t = threadIdx.x;
  for (int i = t; i < 1024; i += 256) h[i] = 0;
  __syncthreads();
  const int c0 = blockIdx.x * CHUNK;
  const int cnt = min(CHUNK, E - c0);
  const int m64 = *flag;
  for (int i = t; i < cnt; i += 256)
    atomicAdd(&h[edge_dst(ei, E, c0 + i, m64) >> 7], 1);
  __syncthreads();
  for (int i = t; i < NB; i += 256)
    if (h[i]) atomicAdd(&bucket_cnt[i], h[i]);
}

// exclusive scan of bucket counts (single block, 256 thr x 4 entries)
__global__ void k_bscan(const int* __restrict__ bucket_cnt, int* __restrict__ bucket_base,
                        int* __restrict__ bucket_cursor, int NB,
                        int* __restrict__ row_ptr, int n, int E) {
  __shared__ int ts[256];
  const int t = threadIdx.x;
  const int b4 = t * 4;
  int a0 = (b4 + 0 < NB) ? bucket_cnt[b4 + 0] : 0;
  int a1 = (b4 + 1 < NB) ? bucket_cnt[b4 + 1] : 0;
  int a2 = (b4 + 2 < NB) ? bucket_cnt[b4 + 2] : 0;
  int a3 = (b4 + 3 < NB) ? bucket_cnt[b4 + 3] : 0;
  int p1 = a0, p2 = p1 + a1, p3 = p2 + a2, tsum = p3 + a3;
  ts[t] = tsum;
  __syncthreads();
  for (int off = 1; off < 256; off <<= 1) {
    int x = (t >= off) ? ts[t - off] : 0;
    __syncthreads();
    ts[t] += x;
    __syncthreads();
  }
  int ex0 = ts[t] - tsum;
  int e[4] = {ex0, ex0 + p1, ex0 + p2, ex0 + p3};
#pragma unroll
  for (int j = 0; j < 4; ++j) {
    int i = b4 + j;
    if (i < NB) { bucket_base[i] = e[j]; bucket_cursor[i] = e[j]; }
  }
  if (t == 0) row_ptr[n] = E + n;   // CSR includes one self-edge per node
}

// LDS-staged multi-split: stage chunk sorted by bucket, flush contiguous runs
__global__ void k_place(const int* __restrict__ ei, int E, const int* __restrict__ flag,
                        int* __restrict__ bucket_cursor, uint2* __restrict__ pairs, int NB) {
  __shared__ int h[1024];        // counts, then reused as global base per bucket
  __shared__ int ex[1024];       // exclusive local offsets (preserved)
  __shared__ int cur[1024];      // placement cursor
  __shared__ int ts[256];
  __shared__ uint2 stage[CHUNK];
  const int t = threadIdx.x;
  const int c0 = blockIdx.x * CHUNK;
  const int cnt = min(CHUNK, E - c0);
  const int m64 = *flag;

  for (int i = t; i < 1024; i += 256) h[i] = 0;
  __syncthreads();

  int es[8], ed[8];
#pragma unroll
  for (int j = 0; j < 8; ++j) {
    int i = t + j * 256;
    es[j] = 0; ed[j] = -1;
    if (i < cnt) {
      es[j] = edge_src(ei, E, c0 + i, m64);
      ed[j] = edge_dst(ei, E, c0 + i, m64);
      atomicAdd(&h[ed[j] >> 7], 1);
    }
  }
  __syncthreads();

  // scan h[0..1023] -> ex (exclusive), two-level
  const int b4 = t * 4;
  int a0 = h[b4], a1 = h[b4 + 1], a2 = h[b4 + 2], a3 = h[b4 + 3];
  int p1 = a0, p2 = p1 + a1, p3 = p2 + a2, tsum = p3 + a3;
  ts[t] = tsum;
  __syncthreads();
  for (int off = 1; off < 256; off <<= 1) {
    int x = (t >= off) ? ts[t - off] : 0;
    __syncthreads();
    ts[t] += x;
    __syncthreads();
  }
  int ex0 = ts[t] - tsum;
  ex[b4] = ex0;       cur[b4] = ex0;
  ex[b4 + 1] = ex0 + p1; cur[b4 + 1] = ex0 + p1;
  ex[b4 + 2] = ex0 + p2; cur[b4 + 2] = ex0 + p2;
  ex[b4 + 3] = ex0 + p3; cur[b4 + 3] = ex0 + p3;
  __syncthreads();

  // place into stage in bucket-sorted order
#pragma unroll
  for (int j = 0; j < 8; ++j) {
    if (ed[j] >= 0) {
      int b = ed[j] >> 7;
      int pos = atomicAdd(&cur[b], 1);
      stage[pos] = make_uint2((u32)es[j], (u32)ed[j]);
    }
  }
  // reserve global space per bucket (h[b] := global base)
  __syncthreads();
  for (int i = t; i < NB; i += 256) {
    int c = h[i];
    if (c > 0) h[i] = atomicAdd(&bucket_cursor[i], c);
  }
  __syncthreads();

  // flush: consecutive i within a bucket -> consecutive global positions
  for (int i = t; i < cnt; i += 256) {
    uint2 p = stage[i];
    int b = (int)(p.y >> 7);
    pairs[h[b] + (i - ex[b])] = p;
  }
}

// per-bucket exact CSR with SELF-EDGE prepended per node:
// node's segment = [self] ++ neighbors; global start = bucket_base + b*128 + excl + t.
#define BMAX 3072
__global__ void k_csr(const uint2* __restrict__ pairs, const int* __restrict__ bucket_cnt,
                      const int* __restrict__ bucket_base, int* __restrict__ row_ptr,
                      float* __restrict__ dinv, int* __restrict__ srcs, int n) {
  __shared__ int h[128], cur[128];
  __shared__ int lsrc[BMAX];
  const int b = blockIdx.x;
  const int t = threadIdx.x;
  const int cnt = bucket_cnt[b];
  const int base = bucket_base[b];
  const int nbase = base + b * 128;          // global base incl. self-edges

  if (t < 128) h[t] = 0;
  __syncthreads();
  for (int i = t; i < cnt; i += 256)
    atomicAdd(&h[pairs[base + i].y & 127], 1);
  __syncthreads();

  // scan 128 (inclusive -> exclusive), all threads hit barriers
  __shared__ int sc[128];
  int v = 0;
  if (t < 128) { v = h[t]; sc[t] = v; }
  __syncthreads();
  for (int off = 1; off < 128; off <<= 1) {
    int x = 0;
    if (t < 128 && t >= off) x = sc[t - off];
    __syncthreads();
    if (t < 128) sc[t] += x;
    __syncthreads();
  }
  if (t < 128) {
    int excl = sc[t] - v;
    cur[t] = excl + t + 1;                   // neighbors start after the self slot
    int node = b * 128 + t;
    if (node < n) {
      row_ptr[node] = nbase + excl + t;
      dinv[node] = rsqrtf(1.0f + (float)v);
      int sp = excl + t;                     // self slot (local)
      if (sp < BMAX) lsrc[sp] = node;
      else srcs[nbase + sp] = node;
    }
  }
  __syncthreads();

  for (int i = t; i < cnt; i += 256) {
    uint2 p = pairs[base + i];
    int pos = atomicAdd(&cur[p.y & 127], 1);
    if (pos < BMAX) lsrc[pos] = (int)p.x;
    else srcs[nbase + pos] = (int)p.x;       // overflow path (statistically never)
  }
  __syncthreads();
  const int lim = min(cnt + 128, BMAX);
  for (int i = t; i < lim; i += 256) srcs[nbase + i] = lsrc[i];
}

// ---- MFMA GEMM, direct global->VGPR (no LDS, no barriers) ----
// G[m][n] = bf16( (A @ Wt^T)[m][n] * dinv[m] ).  Block = 64 rows x N cols,
// 4 waves in a 2x2 grid (wave tile 32 x N/2).
//
// Round-7 change: for this shape (block = 64 rows x full N), an A row is read
// only by the two wc-waves of one block -- there is NO cross-wave reuse worth
// staging.  Rounds 5-6 showed the LDS/DMA/barrier machinery locks stage and
// compute into a low-duty-cycle cycle (70 us, HBM 14%, MfmaUtil 3%, 3.5M bank
// conflicts).  Direct per-lane global loads (2x float4 per m-tile per k-step,
// 128B/row coalesced across the lq groups) + fully unrolled K let 16
// free-running waves/CU keep far more than the ~9KB bandwidth-delay product
// in flight with zero synchronization.  The duplicated wc=0/wc=1 A read hits
// L1/L2, not HBM.
template<int N, int K, bool A_FP32>
__launch_bounds__(256, 4)
__global__ void k_gemm(const void* __restrict__ Ap, const u16* __restrict__ Wt,
                       const float* __restrict__ dinv, u16* __restrict__ G, int M)
{
  constexpr int ESZ = A_FP32 ? 4 : 2;
  constexpr int KS  = K / 32;                // k-steps
  constexpr int NT  = N / 32;                // 16-wide n-tiles per wave (N/2 cols)
  const int t = threadIdx.x;
  const int wave = t >> 6, lane = t & 63;
  const int row0 = blockIdx.x * 64;
  const int wr = wave >> 1, wc = wave & 1;   // 2x2 wave grid
  const int lm = lane & 15, lq = lane >> 4;

  floatx4 acc[2][NT];
#pragma unroll
  for (int i = 0; i < 2; ++i)
#pragma unroll
    for (int j = 0; j < NT; ++j) acc[i][j] = (floatx4)(0.0f);

  int r0 = row0 + wr * 32 + lm;              // m-tile 0 row
  int r1 = r0 + 16;                          // m-tile 1 row
  if (r0 >= M) r0 = M - 1;                   // clamp: garbage rows, stores guarded
  if (r1 >= M) r1 = M - 1;
  const char* pa0 = (const char*)Ap + ((size_t)r0 * K + lq * 8) * ESZ;
  const char* pa1 = (const char*)Ap + ((size_t)r1 * K + lq * 8) * ESZ;
  const u16*  pb  = Wt + (size_t)(wc * (N / 2) + lm) * K + lq * 8;

#pragma unroll
  for (int ks = 0; ks < KS; ++ks) {
    bf16x8 a[2];
    if constexpr (A_FP32) {
      float4 f0 = *(const float4*)(pa0 + ks * 128);
      float4 f1 = *(const float4*)(pa0 + ks * 128 + 16);
      float4 g0 = *(const float4*)(pa1 + ks * 128);
      float4 g1 = *(const float4*)(pa1 + ks * 128 + 16);
      bf16x8 av, bv;
      av[0] = (__bf16)f0.x; av[1] = (__bf16)f0.y; av[2] = (__bf16)f0.z; av[3] = (__bf16)f0.w;
      av[4] = (__bf16)f1.x; av[5] = (__bf16)f1.y; av[6] = (__bf16)f1.z; av[7] = (__bf16)f1.w;
      bv[0] = (__bf16)g0.x; bv[1] = (__bf16)g0.y; bv[2] = (__bf16)g0.z; bv[3] = (__bf16)g0.w;
      bv[4] = (__bf16)g1.x; bv[5] = (__bf16)g1.y; bv[6] = (__bf16)g1.z; bv[7] = (__bf16)g1.w;
      a[0] = av; a[1] = bv;
    } else {
      a[0] = *(const bf16x8*)(pa0 + ks * 64);
      a[1] = *(const bf16x8*)(pa1 + ks * 64);
    }
    bf16x8 b[NT];
#pragma unroll
    for (int nt = 0; nt < NT; ++nt)
      b[nt] = *(const bf16x8*)(pb + (size_t)nt * 16 * K + ks * 32);
#pragma unroll
    for (int nt = 0; nt < NT; ++nt) {
      acc[0][nt] = __builtin_amdgcn_mfma_f32_16x16x32_bf16(a[0], b[nt], acc[0][nt], 0, 0, 0);
      acc[1][nt] = __builtin_amdgcn_mfma_f32_16x16x32_bf16(a[1], b[nt], acc[1][nt], 0, 0, 0);
    }
  }

  // C/D layout: row = (lane>>4)*4 + r, col = lane&15 (m89/m91-verified)
  const int crow0 = row0 + wr * 32 + lq * 4;
#pragma unroll
  for (int mt = 0; mt < 2; ++mt) {
#pragma unroll
    for (int nt = 0; nt < NT; ++nt) {
      const int gc = wc * (N / 2) + nt * 16 + lm;
#pragma unroll
      for (int r = 0; r < 4; ++r) {
        const int gr = crow0 + mt * 16 + r;
        if (gr < M) G[(size_t)gr * N + gc] = f2bf(acc[mt][nt][r] * dinv[gr]);
      }
    }
  }
}

// ---- streaming gather aggregation over CSR (self-edges included) ----
// Each wave owns NPW consecutive nodes; their edges are CONTIGUOUS in srcs.
// 8-edge batches, 2-stage software pipeline (16 gathers in flight), accumulator
// carried across node boundaries; boundary compares are wave-uniform scalars.
template<int F, bool RELU, bool OUT_BF16, int NPW>
__launch_bounds__(256, 4)
__global__ void k_agg(const u16* __restrict__ g, const int* __restrict__ row_ptr,
                      const int* __restrict__ srcs, const float* __restrict__ dinv,
                      const float* __restrict__ bias, void* __restrict__ outp, int n)
{
  const int wid = blockIdx.x * 4 + (threadIdx.x >> 6);
  const int n0 = wid * NPW;
  if (n0 >= n) return;
  const int n1 = min(n0 + NPW, n);
  const int lane = threadIdx.x & 63;
  constexpr int VPL = F / 64;
  const int col = lane * VPL;
  const float b0 = bias[col];
  const float b1 = (VPL == 2) ? bias[col + (VPL - 1)] : 0.f;

  int e    = __builtin_amdgcn_readfirstlane(row_ptr[n0]);
  int eEnd = __builtin_amdgcn_readfirstlane(row_ptr[n1]);
  int cur  = n0;
  int nb   = __builtin_amdgcn_readfirstlane(row_ptr[n0 + 1]);
  float dv = dinv[n0];
  float a0 = 0.f, a1 = 0.f;

  auto fin = [&]() {
    float o0 = dv * a0 + b0;
    if (RELU) o0 = fmaxf(o0, 0.f);
    if constexpr (VPL == 2) {
      float o1 = dv * a1 + b1;
      if (RELU) o1 = fmaxf(o1, 0.f);
      if constexpr (OUT_BF16) {
        u32 pk = (u32)f2bf(o0) | ((u32)f2bf(o1) << 16);
        *(u32*)((u16*)outp + (size_t)cur * F + col) = pk;
      } else {
        *(float2*)((float*)outp + (size_t)cur * F + col) = make_float2(o0, o1);
      }
    } else {
      if constexpr (OUT_BF16) ((u16*)outp)[(size_t)cur * F + col] = f2bf(o0);
      else                    ((float*)outp)[(size_t)cur * F + col] = o0;
    }
    ++cur;
    a0 = 0.f; a1 = 0.f;
    if (cur < n) {
      dv = dinv[cur];
      nb = __builtin_amdgcn_readfirstlane(row_ptr[cur + 1]);
    }
  };

  auto issue = [&](int eb, u32* gv) {
    const int* sp = srcs + eb;               // eb uniform -> scalar loads
#pragma unroll
    for (int j = 0; j < 8; ++j) {
      const int s = sp[j];
      if constexpr (VPL == 2)
        gv[j] = *(const u32*)(g + (size_t)s * F + col);
      else
        gv[j] = (u32)g[(size_t)s * F + col];
    }
  };

  auto consume = [&](int eb, const u32* gv) {
#pragma unroll
    for (int j = 0; j < 8; ++j) {
      if (eb + j == nb) fin();               // uniform compare -> s_cbranch
      if constexpr (VPL == 2) {
        a0 += bf2f((u16)gv[j]);
        a1 += bf2f((u16)(gv[j] >> 16));
      } else {
        a0 += bf2f((u16)gv[j]);
      }
    }
  };

  u32 gvA[8], gvB[8];
  const int rem = (eEnd - e) >> 3;           // full 8-edge batches
  if (rem >= 1) issue(e, gvA);
  if (rem >= 2) issue(e + 8, gvB);
  int i = 0;
  for (; i + 2 < rem; i += 2) {
    consume(e + i * 8, gvA);
    issue(e + (i + 2) * 8, gvA);
    consume(e + (i + 1) * 8, gvB);
    if (i + 3 < rem) issue(e + (i + 3) * 8, gvB);
  }
  if (i < rem) { consume(e + i * 8, gvA); ++i; }
  if (i < rem) { consume(e + i * 8, gvB); ++i; }

  for (int et = e + rem * 8; et < eEnd; ++et) {   // tail edges
    const int s = srcs[et];
    u32 gvt;
    if constexpr (VPL == 2) gvt = *(const u32*)(g + (size_t)s * F + col);
    else                    gvt = (u32)g[(size_t)s * F + col];
    if (et == nb) fin();
    if constexpr (VPL == 2) { a0 += bf2f((u16)gvt); a1 += bf2f((u16)(gvt >> 16)); }
    else                    a0 += bf2f((u16)gvt);
  }
  fin();                                      // last node of this wave
}

extern "C" void kernel_launch(void* const* d_in, const int* in_sizes, int n_in,
                              void* d_out, int out_size, void* d_ws, size_t ws_size,
                              hipStream_t stream)
{
  const float* x  = (const float*)d_in[0];   // [n,256] fp32
  const int*   ei = (const int*)d_in[1];     // [2,E] int32 (or int64 -- detected)
  const float* W1 = (const float*)d_in[2];   // [256,128] fp32
  const float* b1 = (const float*)d_in[3];   // [128] fp32
  const float* W2 = (const float*)d_in[4];   // [128,64] fp32
  const float* b2 = (const float*)d_in[5];   // [64] fp32

  const int n = in_sizes[0] / 256;
  const int E = in_sizes[1] / 2;
  const int NB = (n + 127) >> 7;             // buckets of 128 nodes (<=1024)

  char* ws = (char*)d_ws;
  size_t off = 0;
  auto alloc = [&](size_t bytes) -> void* {
    void* p = ws + off;
    off = (off + bytes + 255) & ~(size_t)255;
    return p;
  };
  int*   row_ptr = (int*)alloc((size_t)(n + 1) * 4);
  int*   bcnt    = (int*)alloc(1024 * 4);
  int*   bbase   = (int*)alloc(1024 * 4);
  int*   bcur    = (int*)alloc(1024 * 4);
  int*   eflag   = (int*)alloc(256);
  float* dinv    = (float*)alloc((size_t)n * 4);
  u16*   Wt1     = (u16*)alloc(256 * 128 * 2);
  u16*   Wt2     = (u16*)alloc(128 * 64 * 2);
  uint2* pairs   = (uint2*)alloc((size_t)E * 8);
  int*   srcs    = (int*)alloc((size_t)(E + n + 512) * 4);   // incl. self-edges + flush pad
  u16*   g1      = (u16*)alloc((size_t)n * 128 * 2);
  u16*   y1      = (u16*)alloc((size_t)n * 128 * 2);
  u16*   g2      = (u16*)alloc((size_t)n * 64 * 2);
  (void)ws_size; (void)n_in; (void)out_size;

  const int TB = 256;
  const int nbC = (E + CHUNK - 1) / CHUNK;

  hipMemsetAsync(bcnt, 0, 1024 * 4, stream);
  k_edgemode<<<1, 64, 0, stream>>>(ei, eflag);
  k_transpose<<<(256 * 128 + 128 * 64 + TB - 1) / TB, TB, 0, stream>>>(W1, W2, Wt1, Wt2);
  k_count<<<nbC, TB, 0, stream>>>(ei, E, eflag, bcnt, NB);
  k_bscan<<<1, TB, 0, stream>>>(bcnt, bbase, bcur, NB, row_ptr, n, E);
  k_place<<<nbC, TB, 0, stream>>>(ei, E, eflag, bcur, pairs, NB);
  k_csr<<<NB, TB, 0, stream>>>(pairs, bcnt, bbase, row_ptr, dinv, srcs, n);

  constexpr int NPW = 8;                     // nodes per wave (streaming agg)
  const int nwaves = (n + NPW - 1) / NPW;
  const int aggGrid = (nwaves + 3) / 4;

  k_gemm<128, 256, true><<<(n + 63) / 64, 256, 0, stream>>>(x, Wt1, dinv, g1, n);
  k_agg<128, true, true, NPW><<<aggGrid, 256, 0, stream>>>(g1, row_ptr, srcs, dinv, b1, y1, n);
  k_gemm<64, 128, false><<<(n + 63) / 64, 256, 0, stream>>>(y1, Wt2, dinv, g2, n);
  k_agg<64, false, false, NPW><<<aggGrid, 256, 0, stream>>>(g2, row_ptr, srcs, dinv, b2, d_out, n);
}

// Round 4
// 375.041 us; speedup vs baseline: 1.0620x; 1.0620x over previous
//
#include <hip/hip_runtime.h>
#include <stdint.h>

typedef unsigned short u16;
typedef unsigned int u32;
typedef __bf16 bf16x8 __attribute__((ext_vector_type(8)));
typedef float floatx4 __attribute__((ext_vector_type(4)));

static __device__ __forceinline__ float bf2f(u16 u) {
  union { u32 i; float f; } v; v.i = ((u32)u) << 16; return v.f;
}
static __device__ __forceinline__ u16 f2bf(float f) {
  union { float f; u32 i; } v; v.f = f;
  u32 u = v.i;
  return (u16)((u + 0x7fffu + ((u >> 16) & 1u)) >> 16);  // RNE
}

// async 16B/lane global->LDS DMA: lds dst = base + lane*16 (wave-uniform base)
static __device__ __forceinline__ void gload_lds16(const void* g, void* l) {
  __builtin_amdgcn_global_load_lds(
      (const __attribute__((address_space(1))) void*)g,
      (__attribute__((address_space(3))) void*)l, 16, 0, 0);
}

// ---- edge dtype detector: int64 layout <=> odd int32 words are all high-halves (0) ----
__global__ void k_edgemode(const int* __restrict__ ei, int* __restrict__ flag) {
  int t = threadIdx.x;                       // 64 threads, 1 wave
  int v = ei[2 * t + 1];                     // odd positions among first 128 ints
  unsigned long long b = __ballot(v == 0);
  if (t == 0) *flag = (b == ~0ull) ? 1 : 0;  // all zero -> int64 buffer
}

static __device__ __forceinline__ int edge_src(const int* ei, int E, int i, int m64) {
  return m64 ? ei[2 * (size_t)i] : ei[i];
}
static __device__ __forceinline__ int edge_dst(const int* ei, int E, int i, int m64) {
  return m64 ? ei[2 * (size_t)E + 2 * (size_t)i] : ei[(size_t)E + i];
}

// ---- W transpose + fp32->bf16: Wt[n][k] = bf16(W[k][n]) ----
__global__ void k_transpose(const float* __restrict__ W1, const float* __restrict__ W2,
                            u16* __restrict__ Wt1, u16* __restrict__ Wt2) {
  int i = blockIdx.x * 256 + threadIdx.x;
  if (i < 256 * 128) {
    int k = i >> 7, c = i & 127;
    Wt1[c * 256 + k] = f2bf(W1[i]);
  } else {
    int j = i - 256 * 128;
    if (j < 128 * 64) {
      int k = j >> 6, c = j & 63;
      Wt2[c * 128 + k] = f2bf(W2[j]);
    }
  }
}

// ======== bucket partition: bucket b = dst>>7 (128 nodes per bucket) ========
#define CHUNK 2048

// per-chunk LDS histogram -> global bucket counts
__global__ void k_count(const int* __restrict__ ei, int E, const int* __restrict__ flag,
                        int* __restrict__ bucket_cnt, int NB) {
  __shared__ int h[1024];
  const int t = threadIdx.x;
  for (int i = t; i < 1024; i += 256) h[i] = 0;
  __syncthreads();
  const int c0 = blockIdx.x * CHUNK;
  const int cnt = min(CHUNK, E - c0);
  const int m64 = *flag;
  for (int i = t; i < cnt; i += 256)
    atomicAdd(&h[edge_dst(ei, E, c0 + i, m64) >> 7], 1);
  __syncthreads();
  for (int i = t; i < NB; i += 256)
    if (h[i]) atomicAdd(&bucket_cnt[i], h[i]);
}

// exclusive scan of bucket counts (single block, 256 thr x 4 entries)
__global__ void k_bscan(const int* __restrict__ bucket_cnt, int* __restrict__ bucket_base,
                        int* __restrict__ bucket_cursor, int NB,
                        int* __restrict__ row_ptr, int n, int E) {
  __shared__ int ts[256];
  const int t = threadIdx.x;
  const int b4 = t * 4;
  int a0 = (b4 + 0 < NB) ? bucket_cnt[b4 + 0] : 0;
  int a1 = (b4 + 1 < NB) ? bucket_cnt[b4 + 1] : 0;
  int a2 = (b4 + 2 < NB) ? bucket_cnt[b4 + 2] : 0;
  int a3 = (b4 + 3 < NB) ? bucket_cnt[b4 + 3] : 0;
  int p1 = a0, p2 = p1 + a1, p3 = p2 + a2, tsum = p3 + a3;
  ts[t] = tsum;
  __syncthreads();
  for (int off = 1; off < 256; off <<= 1) {
    int x = (t >= off) ? ts[t - off] : 0;
    __syncthreads();
    ts[t] += x;
    __syncthreads();
  }
  int ex0 = ts[t] - tsum;
  int e[4] = {ex0, ex0 + p1, ex0 + p2, ex0 + p3};
#pragma unroll
  for (int j = 0; j < 4; ++j) {
    int i = b4 + j;
    if (i < NB) { bucket_base[i] = e[j]; bucket_cursor[i] = e[j]; }
  }
  if (t == 0) row_ptr[n] = E + n;   // CSR includes one self-edge per node
}

// LDS-staged multi-split: stage chunk sorted by bucket, flush contiguous runs
__global__ void k_place(const int* __restrict__ ei, int E, const int* __restrict__ flag,
                        int* __restrict__ bucket_cursor, uint2* __restrict__ pairs, int NB) {
  __shared__ int h[1024];        // counts, then reused as global base per bucket
  __shared__ int ex[1024];       // exclusive local offsets (preserved)
  __shared__ int cur[1024];      // placement cursor
  __shared__ int ts[256];
  __shared__ uint2 stage[CHUNK];
  const int t = threadIdx.x;
  const int c0 = blockIdx.x * CHUNK;
  const int cnt = min(CHUNK, E - c0);
  const int m64 = *flag;

  for (int i = t; i < 1024; i += 256) h[i] = 0;
  __syncthreads();

  int es[8], ed[8];
#pragma unroll
  for (int j = 0; j < 8; ++j) {
    int i = t + j * 256;
    es[j] = 0; ed[j] = -1;
    if (i < cnt) {
      es[j] = edge_src(ei, E, c0 + i, m64);
      ed[j] = edge_dst(ei, E, c0 + i, m64);
      atomicAdd(&h[ed[j] >> 7], 1);
    }
  }
  __syncthreads();

  // scan h[0..1023] -> ex (exclusive), two-level
  const int b4 = t * 4;
  int a0 = h[b4], a1 = h[b4 + 1], a2 = h[b4 + 2], a3 = h[b4 + 3];
  int p1 = a0, p2 = p1 + a1, p3 = p2 + a2, tsum = p3 + a3;
  ts[t] = tsum;
  __syncthreads();
  for (int off = 1; off < 256; off <<= 1) {
    int x = (t >= off) ? ts[t - off] : 0;
    __syncthreads();
    ts[t] += x;
    __syncthreads();
  }
  int ex0 = ts[t] - tsum;
  ex[b4] = ex0;       cur[b4] = ex0;
  ex[b4 + 1] = ex0 + p1; cur[b4 + 1] = ex0 + p1;
  ex[b4 + 2] = ex0 + p2; cur[b4 + 2] = ex0 + p2;
  ex[b4 + 3] = ex0 + p3; cur[b4 + 3] = ex0 + p3;
  __syncthreads();

  // place into stage in bucket-sorted order
#pragma unroll
  for (int j = 0; j < 8; ++j) {
    if (ed[j] >= 0) {
      int b = ed[j] >> 7;
      int pos = atomicAdd(&cur[b], 1);
      stage[pos] = make_uint2((u32)es[j], (u32)ed[j]);
    }
  }
  // reserve global space per bucket (h[b] := global base)
  __syncthreads();
  for (int i = t; i < NB; i += 256) {
    int c = h[i];
    if (c > 0) h[i] = atomicAdd(&bucket_cursor[i], c);
  }
  __syncthreads();

  // flush: consecutive i within a bucket -> consecutive global positions
  for (int i = t; i < cnt; i += 256) {
    uint2 p = stage[i];
    int b = (int)(p.y >> 7);
    pairs[h[b] + (i - ex[b])] = p;
  }
}

// per-bucket exact CSR with SELF-EDGE prepended per node:
// node's segment = [self] ++ neighbors; global start = bucket_base + b*128 + excl + t.
#define BMAX 3072
__global__ void k_csr(const uint2* __restrict__ pairs, const int* __restrict__ bucket_cnt,
                      const int* __restrict__ bucket_base, int* __restrict__ row_ptr,
                      float* __restrict__ dinv, int* __restrict__ srcs, int n) {
  __shared__ int h[128], cur[128];
  __shared__ int lsrc[BMAX];
  const int b = blockIdx.x;
  const int t = threadIdx.x;
  const int cnt = bucket_cnt[b];
  const int base = bucket_base[b];
  const int nbase = base + b * 128;          // global base incl. self-edges

  if (t < 128) h[t] = 0;
  __syncthreads();
  for (int i = t; i < cnt; i += 256)
    atomicAdd(&h[pairs[base + i].y & 127], 1);
  __syncthreads();

  // scan 128 (inclusive -> exclusive), all threads hit barriers
  __shared__ int sc[128];
  int v = 0;
  if (t < 128) { v = h[t]; sc[t] = v; }
  __syncthreads();
  for (int off = 1; off < 128; off <<= 1) {
    int x = 0;
    if (t < 128 && t >= off) x = sc[t - off];
    __syncthreads();
    if (t < 128) sc[t] += x;
    __syncthreads();
  }
  if (t < 128) {
    int excl = sc[t] - v;
    cur[t] = excl + t + 1;                   // neighbors start after the self slot
    int node = b * 128 + t;
    if (node < n) {
      row_ptr[node] = nbase + excl + t;
      dinv[node] = rsqrtf(1.0f + (float)v);
      int sp = excl + t;                     // self slot (local)
      if (sp < BMAX) lsrc[sp] = node;
      else srcs[nbase + sp] = node;
    }
  }
  __syncthreads();

  for (int i = t; i < cnt; i += 256) {
    uint2 p = pairs[base + i];
    int pos = atomicAdd(&cur[p.y & 127], 1);
    if (pos < BMAX) lsrc[pos] = (int)p.x;
    else srcs[nbase + pos] = (int)p.x;       // overflow path (statistically never)
  }
  __syncthreads();
  const int lim = min(cnt + 128, BMAX);
  for (int i = t; i < lim; i += 256) srcs[nbase + i] = lsrc[i];
}

// ---- MFMA GEMM: double-buffered async chunk pipeline, counted vmcnt ----
// G[m][n] = bf16( (A @ Wt^T)[m][n] * dinv[m] ).  Block = 64 rows x N cols,
// 4 waves in a 2x2 grid.  K split into CHK-col chunks; chunk c+1's
// global_load_lds issues BEFORE chunk c's compute, and the pre-compute wait
// is s_waitcnt vmcnt(IPW) -- the next chunk's DMAs stay in flight across the
// raw s_barrier (never drain to 0 in the loop; __syncthreads would emit
// vmcnt(0) and re-create the round-5/6 lockstep that capped HBM at ~13%).
// B fragments are loaded to registers BEFORE the stage issues each iteration
// so the compiler's B-wait is vmcnt(IPW), not a FIFO drain of the DMA queue.
// LDS layout is XOR-swizzled via pre-swizzled GLOBAL source (linear DMA dest,
// m173 pattern): slot ^= row_in_issue * (8/RPI) -> 2-way-max bank aliasing
// on ds_read_b128 (2-way is free), vs 4-way/3.5M conflicts in round 6.
template<int N, int K, int CHK, bool A_FP32>
__launch_bounds__(256, 4)
__global__ void k_gemm(const void* __restrict__ Ap, const u16* __restrict__ Wt,
                       const float* __restrict__ dinv, u16* __restrict__ G, int M)
{
  constexpr int ESZ  = A_FP32 ? 4 : 2;
  constexpr int BPR  = K * ESZ;              // bytes per full A row
  constexpr int BPRC = CHK * ESZ;            // bytes per row within a chunk
  constexpr int RPI  = 1024 / BPRC;          // rows per 1KB DMA issue (4 or 8)
  constexpr int NISS = 64 / RPI;             // issues per chunk
  constexpr int STRIDE = 1024 + 16;          // +16B: issue-to-issue bank rotation
  constexpr int NCH  = K / CHK;              // chunks (4 for gemm1, 2 for gemm2)
  constexpr int KSC  = CHK / 32;             // k-steps per chunk
  constexpr int IPW  = NISS / 4;             // DMA issues per wave per chunk
  constexpr int LPR  = BPRC / 16;            // lanes covering one row in an issue
  constexpr int SWM  = 8 / RPI;              // swizzle multiplier (16B slots)
  constexpr int NT   = N / 32;               // 16-wide n-tiles per wave
  __shared__ char lds[2 * NISS * STRIDE];
  const int t = threadIdx.x;
  const int wave = t >> 6, lane = t & 63;
  const int row0 = blockIdx.x * 64;
  const int wr = wave >> 1, wc = wave & 1;   // 2x2 wave grid
  const int lm = lane & 15, lq = lane >> 4;

  // per-lane DMA source offset within an issue: row-in-issue + swizzled slot.
  // LDS dest is linear (hw: base + lane*16); swizzle lives in the source addr.
  const int ril  = lane / LPR;                       // row in issue (0..RPI-1)
  const int scol = ((lane % LPR) ^ (ril * SWM)) * 16;

  auto stage = [&](int kc) {
    char* buf = lds + (size_t)(kc & 1) * (NISS * STRIDE);
    const size_t kb = (size_t)kc * BPRC;
#pragma unroll
    for (int i = 0; i < IPW; ++i) {
      const int g = wave * IPW + i;
      int r0 = row0 + g * RPI;
      if (r0 < M) {
        if (r0 > M - RPI) r0 = M - RPI;      // clamp (M % RPI == 0 here)
        gload_lds16((const char*)Ap + (size_t)(r0 + ril) * BPR + kb + scol,
                    buf + g * STRIDE);
      }
    }
  };

  floatx4 acc[2][NT];
#pragma unroll
  for (int i = 0; i < 2; ++i)
#pragma unroll
    for (int j = 0; j < NT; ++j) acc[i][j] = (floatx4)(0.0f);

  const int arow = wr * 32 + lm;             // A row for m-tile 0 (m-tile 1: +16)
  const u16* pb = Wt + (size_t)(wc * (N / 2) + lm) * K + lq * 8;

  stage(0);                                  // prologue

#pragma unroll
  for (int c = 0; c < NCH; ++c) {
    // B fragments for chunk c -- issued BEFORE next chunk's DMA (see header)
    bf16x8 breg[KSC][NT];
#pragma unroll
    for (int ksl = 0; ksl < KSC; ++ksl)
#pragma unroll
      for (int nt = 0; nt < NT; ++nt)
        breg[ksl][nt] = *(const bf16x8*)(pb + (size_t)nt * 16 * K + (c * KSC + ksl) * 32);

    if (c + 1 < NCH) {
      stage(c + 1);
      asm volatile("s_waitcnt vmcnt(%0)" :: "i"(IPW) : "memory");
    } else {
      asm volatile("s_waitcnt vmcnt(0)" ::: "memory");
    }
    __builtin_amdgcn_sched_barrier(0);
    __builtin_amdgcn_s_barrier();            // all waves' chunk-c DMA landed
    __builtin_amdgcn_sched_barrier(0);

    const char* buf = lds + (size_t)(c & 1) * (NISS * STRIDE);
#pragma unroll
    for (int ksl = 0; ksl < KSC; ++ksl) {
      bf16x8 a[2];
#pragma unroll
      for (int mt = 0; mt < 2; ++mt) {
        const int r = arow + mt * 16;
        const int cb = (ksl * 32 + lq * 8) * ESZ;
        const char* p = buf + (r / RPI) * STRIDE + (r % RPI) * BPRC
                        + (cb ^ ((r % RPI) * SWM * 16));
        if constexpr (A_FP32) {
          float4 f0 = *(const float4*)p;
          float4 f1 = *(const float4*)(p + 16);
          bf16x8 av;
          av[0] = (__bf16)f0.x; av[1] = (__bf16)f0.y; av[2] = (__bf16)f0.z; av[3] = (__bf16)f0.w;
          av[4] = (__bf16)f1.x; av[5] = (__bf16)f1.y; av[6] = (__bf16)f1.z; av[7] = (__bf16)f1.w;
          a[mt] = av;
        } else {
          a[mt] = *(const bf16x8*)p;
        }
      }
#pragma unroll
      for (int nt = 0; nt < NT; ++nt) {
        acc[0][nt] = __builtin_amdgcn_mfma_f32_16x16x32_bf16(a[0], breg[ksl][nt], acc[0][nt], 0, 0, 0);
        acc[1][nt] = __builtin_amdgcn_mfma_f32_16x16x32_bf16(a[1], breg[ksl][nt], acc[1][nt], 0, 0, 0);
      }
    }
    __builtin_amdgcn_sched_barrier(0);
    __builtin_amdgcn_s_barrier();            // all reads done before buffer reuse
  }

  // C/D layout: row = (lane>>4)*4 + r, col = lane&15 (m89/m91-verified)
  const int crow0 = row0 + wr * 32 + lq * 4;
#pragma unroll
  for (int mt = 0; mt < 2; ++mt) {
#pragma unroll
    for (int nt = 0; nt < NT; ++nt) {
      const int gc = wc * (N / 2) + nt * 16 + lm;
#pragma unroll
      for (int r = 0; r < 4; ++r) {
        const int gr = crow0 + mt * 16 + r;
        if (gr < M) G[(size_t)gr * N + gc] = f2bf(acc[mt][nt][r] * dinv[gr]);
      }
    }
  }
}

// ---- streaming gather aggregation over CSR (self-edges included) ----
// Each wave owns NPW consecutive nodes; their edges are CONTIGUOUS in srcs.
// 8-edge batches, 2-stage software pipeline (16 gathers in flight), accumulator
// carried across node boundaries; boundary compares are wave-uniform scalars.
template<int F, bool RELU, bool OUT_BF16, int NPW>
__launch_bounds__(256, 4)
__global__ void k_agg(const u16* __restrict__ g, const int* __restrict__ row_ptr,
                      const int* __restrict__ srcs, const float* __restrict__ dinv,
                      const float* __restrict__ bias, void* __restrict__ outp, int n)
{
  const int wid = blockIdx.x * 4 + (threadIdx.x >> 6);
  const int n0 = wid * NPW;
  if (n0 >= n) return;
  const int n1 = min(n0 + NPW, n);
  const int lane = threadIdx.x & 63;
  constexpr int VPL = F / 64;
  const int col = lane * VPL;
  const float b0 = bias[col];
  const float b1 = (VPL == 2) ? bias[col + (VPL - 1)] : 0.f;

  int e    = __builtin_amdgcn_readfirstlane(row_ptr[n0]);
  int eEnd = __builtin_amdgcn_readfirstlane(row_ptr[n1]);
  int cur  = n0;
  int nb   = __builtin_amdgcn_readfirstlane(row_ptr[n0 + 1]);
  float dv = dinv[n0];
  float a0 = 0.f, a1 = 0.f;

  auto fin = [&]() {
    float o0 = dv * a0 + b0;
    if (RELU) o0 = fmaxf(o0, 0.f);
    if constexpr (VPL == 2) {
      float o1 = dv * a1 + b1;
      if (RELU) o1 = fmaxf(o1, 0.f);
      if constexpr (OUT_BF16) {
        u32 pk = (u32)f2bf(o0) | ((u32)f2bf(o1) << 16);
        *(u32*)((u16*)outp + (size_t)cur * F + col) = pk;
      } else {
        *(float2*)((float*)outp + (size_t)cur * F + col) = make_float2(o0, o1);
      }
    } else {
      if constexpr (OUT_BF16) ((u16*)outp)[(size_t)cur * F + col] = f2bf(o0);
      else                    ((float*)outp)[(size_t)cur * F + col] = o0;
    }
    ++cur;
    a0 = 0.f; a1 = 0.f;
    if (cur < n) {
      dv = dinv[cur];
      nb = __builtin_amdgcn_readfirstlane(row_ptr[cur + 1]);
    }
  };

  auto issue = [&](int eb, u32* gv) {
    const int* sp = srcs + eb;               // eb uniform -> scalar loads
#pragma unroll
    for (int j = 0; j < 8; ++j) {
      const int s = sp[j];
      if constexpr (VPL == 2)
        gv[j] = *(const u32*)(g + (size_t)s * F + col);
      else
        gv[j] = (u32)g[(size_t)s * F + col];
    }
  };

  auto consume = [&](int eb, const u32* gv) {
#pragma unroll
    for (int j = 0; j < 8; ++j) {
      if (eb + j == nb) fin();               // uniform compare -> s_cbranch
      if constexpr (VPL == 2) {
        a0 += bf2f((u16)gv[j]);
        a1 += bf2f((u16)(gv[j] >> 16));
      } else {
        a0 += bf2f((u16)gv[j]);
      }
    }
  };

  u32 gvA[8], gvB[8];
  const int rem = (eEnd - e) >> 3;           // full 8-edge batches
  if (rem >= 1) issue(e, gvA);
  if (rem >= 2) issue(e + 8, gvB);
  int i = 0;
  for (; i + 2 < rem; i += 2) {
    consume(e + i * 8, gvA);
    issue(e + (i + 2) * 8, gvA);
    consume(e + (i + 1) * 8, gvB);
    if (i + 3 < rem) issue(e + (i + 3) * 8, gvB);
  }
  if (i < rem) { consume(e + i * 8, gvA); ++i; }
  if (i < rem) { consume(e + i * 8, gvB); ++i; }

  for (int et = e + rem * 8; et < eEnd; ++et) {   // tail edges
    const int s = srcs[et];
    u32 gvt;
    if constexpr (VPL == 2) gvt = *(const u32*)(g + (size_t)s * F + col);
    else                    gvt = (u32)g[(size_t)s * F + col];
    if (et == nb) fin();
    if constexpr (VPL == 2) { a0 += bf2f((u16)gvt); a1 += bf2f((u16)(gvt >> 16)); }
    else                    a0 += bf2f((u16)gvt);
  }
  fin();                                      // last node of this wave
}

extern "C" void kernel_launch(void* const* d_in, const int* in_sizes, int n_in,
                              void* d_out, int out_size, void* d_ws, size_t ws_size,
                              hipStream_t stream)
{
  const float* x  = (const float*)d_in[0];   // [n,256] fp32
  const int*   ei = (const int*)d_in[1];     // [2,E] int32 (or int64 -- detected)
  const float* W1 = (const float*)d_in[2];   // [256,128] fp32
  const float* b1 = (const float*)d_in[3];   // [128] fp32
  const float* W2 = (const float*)d_in[4];   // [128,64] fp32
  const float* b2 = (const float*)d_in[5];   // [64] fp32

  const int n = in_sizes[0] / 256;
  const int E = in_sizes[1] / 2;
  const int NB = (n + 127) >> 7;             // buckets of 128 nodes (<=1024)

  char* ws = (char*)d_ws;
  size_t off = 0;
  auto alloc = [&](size_t bytes) -> void* {
    void* p = ws + off;
    off = (off + bytes + 255) & ~(size_t)255;
    return p;
  };
  int*   row_ptr = (int*)alloc((size_t)(n + 1) * 4);
  int*   bcnt    = (int*)alloc(1024 * 4);
  int*   bbase   = (int*)alloc(1024 * 4);
  int*   bcur    = (int*)alloc(1024 * 4);
  int*   eflag   = (int*)alloc(256);
  float* dinv    = (float*)alloc((size_t)n * 4);
  u16*   Wt1     = (u16*)alloc(256 * 128 * 2);
  u16*   Wt2     = (u16*)alloc(128 * 64 * 2);
  uint2* pairs   = (uint2*)alloc((size_t)E * 8);
  int*   srcs    = (int*)alloc((size_t)(E + n + 512) * 4);   // incl. self-edges + flush pad
  u16*   g1      = (u16*)alloc((size_t)n * 128 * 2);
  u16*   y1      = (u16*)alloc((size_t)n * 128 * 2);
  u16*   g2      = (u16*)alloc((size_t)n * 64 * 2);
  (void)ws_size; (void)n_in; (void)out_size;

  const int TB = 256;
  const int nbC = (E + CHUNK - 1) / CHUNK;

  hipMemsetAsync(bcnt, 0, 1024 * 4, stream);
  k_edgemode<<<1, 64, 0, stream>>>(ei, eflag);
  k_transpose<<<(256 * 128 + 128 * 64 + TB - 1) / TB, TB, 0, stream>>>(W1, W2, Wt1, Wt2);
  k_count<<<nbC, TB, 0, stream>>>(ei, E, eflag, bcnt, NB);
  k_bscan<<<1, TB, 0, stream>>>(bcnt, bbase, bcur, NB, row_ptr, n, E);
  k_place<<<nbC, TB, 0, stream>>>(ei, E, eflag, bcur, pairs, NB);
  k_csr<<<NB, TB, 0, stream>>>(pairs, bcnt, bbase, row_ptr, dinv, srcs, n);

  constexpr int NPW = 8;                     // nodes per wave (streaming agg)
  const int nwaves = (n + NPW - 1) / NPW;
  const int aggGrid = (nwaves + 3) / 4;

  k_gemm<128, 256, 64, true><<<(n + 63) / 64, 256, 0, stream>>>(x, Wt1, dinv, g1, n);
  k_agg<128, true, true, NPW><<<aggGrid, 256, 0, stream>>>(g1, row_ptr, srcs, dinv, b1, y1, n);
  k_gemm<64, 128, 64, false><<<(n + 63) / 64, 256, 0, stream>>>(y1, Wt2, dinv, g2, n);
  k_agg<64, false, false, NPW><<<aggGrid, 256, 0, stream>>>(g2, row_ptr, srcs, dinv, b2, d_out, n);
}